// Round 2
// baseline (464.864 us; speedup 1.0000x reference)
//
#include <hip/hip_runtime.h>

// ---------------------------------------------------------------------------
// In2MA: windowed dual attention. B=4, C=64, H=W=256, WIN=8, HEADS=8, INNER=64
// 4096 windows of 64 tokens x 64 ch. One 256-thread block per window.
// R2: fp32 activations in LDS + split-bf16 (hi/lo) MFMA matmuls ->
// effectively fp32 end-to-end (per-matmul rel err ~2^-16). 5 LDS buffers,
// 77312 B -> 2 blocks/CU.
// ---------------------------------------------------------------------------

typedef __attribute__((ext_vector_type(8))) short short8;   // 8 bf16 (4 VGPRs)
typedef __attribute__((ext_vector_type(4))) float floatx4;  // MFMA accum

#define CCH  64
#define HH   256
#define WWD  256
#define HWsz (HH*WWD)
#define CHW  (CCH*HH*WWD)

// weight plane element offsets (hi plane at [0,WTOT), lo plane at [WTOT,2*WTOT))
#define OWPQ  0      // W_pan_q    32x32
#define OWPK  1024   // W_pan_k    32x32
#define OWV1  2048   // W_v1       64x64
#define OWV2  6144   // W_v2       64x64
#define OWK2  10240  // W_k2       32x64
#define OWQ1C 12288  // W_q1c      32x64
#define OWK1C 14336  // W_k1c      32x64
#define OWIO  16384  // W_inner_out 64x64
#define OWINT 20480  // W_inter_out 64x64
#define WTOT  24576

__device__ __forceinline__ unsigned int f2bf_u(float f) {   // RNE, value in low 16
    unsigned int u = __builtin_bit_cast(unsigned int, f);
    u += 0x7FFFu + ((u >> 16) & 1u);
    return u >> 16;
}
__device__ __forceinline__ float bfu2f(unsigned int b) {
    return __builtin_bit_cast(float, b << 16);
}

// ---------------------------------------------------------------------------
// Projection: O(64xN) = A(64xK) @ W(NxK)^T, all effectively fp32.
// A: fp32 LDS, row stride SA (SA*4 % 16 == 0 for ds_read_b128).
// W: two bf16 planes (hi, lo) in global, row-major NxK.
// O: fp32 LDS, row stride SO.
// Wave w owns output rows [16w,16w+16): strip-local, chained calls need no
// barrier. MFMA 16x16x32_bf16 layouts (m89/m120 verified):
//   A: lane holds A[m=lane&15][k=quad*8+j]; B: lane holds W[n=lane&15][k=...]
//   D: lane holds D[row=quad*4+r][col=lane&15]
// Split trick: A@W = Ah@Wh + Al@Wh + Ah@Wl  (drop Al@Wl ~2^-18)
// ---------------------------------------------------------------------------
template <int K, int N, int SA, int SO>
__device__ __forceinline__ void proj(const float* __restrict__ A,
                                     const unsigned short* __restrict__ Wh,
                                     const unsigned short* __restrict__ Wl,
                                     float* __restrict__ O,
                                     int wave, int lane) {
    constexpr int KS = K / 32;
    constexpr int NT = N / 16;
    const int l15 = lane & 15;
    const int quad = lane >> 4;
    const int m0 = wave * 16;

    union Frag { short8 v; unsigned int u[4]; };
    Frag ah[KS], al[KS];
#pragma unroll
    for (int kk = 0; kk < KS; ++kk) {
        const float4* ap = (const float4*)(A + (m0 + l15) * SA + kk * 32 + quad * 8);
        float4 fa = ap[0], fb = ap[1];
        float ff[8] = {fa.x, fa.y, fa.z, fa.w, fb.x, fb.y, fb.z, fb.w};
#pragma unroll
        for (int j2 = 0; j2 < 4; ++j2) {
            float f0 = ff[2 * j2], f1 = ff[2 * j2 + 1];
            unsigned int h0 = f2bf_u(f0), h1 = f2bf_u(f1);
            float r0 = f0 - bfu2f(h0), r1 = f1 - bfu2f(h1);
            ah[kk].u[j2] = h0 | (h1 << 16);
            al[kk].u[j2] = f2bf_u(r0) | (f2bf_u(r1) << 16);
        }
    }

#pragma unroll
    for (int nt = 0; nt < NT; ++nt) {
        floatx4 acc = {0.f, 0.f, 0.f, 0.f};
#pragma unroll
        for (int kk = 0; kk < KS; ++kk) {
            const int wo = (nt * 16 + l15) * K + kk * 32 + quad * 8;
            short8 bh = *(const short8*)(Wh + wo);
            short8 bl = *(const short8*)(Wl + wo);
            acc = __builtin_amdgcn_mfma_f32_16x16x32_bf16(ah[kk].v, bh, acc, 0, 0, 0);
            acc = __builtin_amdgcn_mfma_f32_16x16x32_bf16(al[kk].v, bh, acc, 0, 0, 0);
            acc = __builtin_amdgcn_mfma_f32_16x16x32_bf16(ah[kk].v, bl, acc, 0, 0, 0);
        }
#pragma unroll
        for (int r = 0; r < 4; ++r)
            O[(m0 + quad * 4 + r) * SO + nt * 16 + l15] = acc[r];
    }
}

// ---------------------------------------------------------------------------
// Weight fp32 -> bf16 hi/lo planes (once per launch; ws re-poisoned each call)
// ---------------------------------------------------------------------------
__global__ void cvt_w(const float* __restrict__ w0, const float* __restrict__ w1,
                      const float* __restrict__ w2, const float* __restrict__ w3,
                      const float* __restrict__ w4, const float* __restrict__ w5,
                      const float* __restrict__ w6, const float* __restrict__ w7,
                      const float* __restrict__ w8, unsigned short* __restrict__ o) {
    int i = blockIdx.x * 256 + threadIdx.x;
    const float* src; int off;
    if      (i < 1024)  { src = w0; off = 0; }
    else if (i < 2048)  { src = w1; off = 1024; }
    else if (i < 6144)  { src = w2; off = 2048; }
    else if (i < 10240) { src = w3; off = 6144; }
    else if (i < 12288) { src = w4; off = 10240; }
    else if (i < 14336) { src = w5; off = 12288; }
    else if (i < 16384) { src = w6; off = 14336; }
    else if (i < 20480) { src = w7; off = 16384; }
    else                { src = w8; off = 20480; }
    float f = src[i - off];
    unsigned int h = f2bf_u(f);
    o[i] = (unsigned short)h;
    o[WTOT + i] = (unsigned short)f2bf_u(f - bfu2f(h));
}

// ---------------------------------------------------------------------------
// Main fused kernel: one block per window. LDS plan (fp32, strides in floats):
//  s_xf (68): xf (phA) -> out1 (phC)                         17408 B
//  s_cat(68): pan cols0-31 + q1c cols32-63 -> cat -> out2    17408 B
//  s_v1 (66): v1 -> x_v2 -> final                            16896 B
//  s_qk (66): pan_q cols0-31, pan_k cols32-63                16896 B
//  s_k2 (34): k1c -> x_k2                                     8704 B
// total 77312 B  -> 2 blocks/CU
// ---------------------------------------------------------------------------
__global__ __launch_bounds__(256, 2) void in2ma_main(
    const float* __restrict__ x, const float* __restrict__ pan,
    const float* __restrict__ posi, const float* __restrict__ posc,
    const unsigned short* __restrict__ wb, float* __restrict__ out) {
    __shared__ __align__(16) float s_xf[64 * 68];
    __shared__ __align__(16) float s_cat[64 * 68];
    __shared__ __align__(16) float s_v1[64 * 66];
    __shared__ __align__(16) float s_qk[64 * 66];
    __shared__ __align__(16) float s_k2[64 * 34];

    const int tid  = threadIdx.x;
    const int wave = tid >> 6;
    const int lane = tid & 63;
    const int wid  = blockIdx.x;
    const int b    = wid >> 10;
    const int hn_i = (wid >> 5) & 31;
    const int wn_i = wid & 31;
    const int h0 = hn_i * 8, w0 = wn_i * 8;

    const float scale = 0.35355339059327373f;  // 8^-0.5 (both attentions)
    const unsigned short* wlo = wb + WTOT;

    // ---- S0: stage x window -> s_xf, pan window -> s_cat cols 0-31 (fp32) ----
    {
        const int c = tid >> 2, i = tid & 3;
        const float* xp = x + (size_t)b * CHW + (size_t)c * HWsz + (size_t)h0 * WWD + w0;
#pragma unroll
        for (int r = 0; r < 2; ++r) {
            const int hl = i * 2 + r;
            const float4* p = (const float4*)(xp + hl * WWD);
            float4 a = p[0], q = p[1];
            float* d = s_xf + (hl * 8) * 68 + c;
            d[0 * 68] = a.x; d[1 * 68] = a.y; d[2 * 68] = a.z; d[3 * 68] = a.w;
            d[4 * 68] = q.x; d[5 * 68] = q.y; d[6 * 68] = q.z; d[7 * 68] = q.w;
        }
        if (tid < 128) {
            const int c2 = tid >> 2, i2 = tid & 3;
            const float* pp = pan + (size_t)b * (CHW / 2) + (size_t)c2 * HWsz + (size_t)h0 * WWD + w0;
#pragma unroll
            for (int r = 0; r < 2; ++r) {
                const int hl = i2 * 2 + r;
                const float4* p = (const float4*)(pp + hl * WWD);
                float4 a = p[0], q = p[1];
                float* d = s_cat + (hl * 8) * 68 + c2;
                d[0 * 68] = a.x; d[1 * 68] = a.y; d[2 * 68] = a.z; d[3 * 68] = a.w;
                d[4 * 68] = q.x; d[5 * 68] = q.y; d[6 * 68] = q.z; d[7 * 68] = q.w;
            }
        }
    }
    __syncthreads();

    // ---- Phase A: projections (strip-local; no intra-phase barriers) ----
    proj<32, 32, 68, 66>(s_cat,      wb + OWPQ,  wlo + OWPQ,  s_qk,      wave, lane); // pan_q
    proj<32, 32, 68, 66>(s_cat,      wb + OWPK,  wlo + OWPK,  s_qk + 32, wave, lane); // pan_k
    proj<64, 64, 68, 66>(s_xf,       wb + OWV1,  wlo + OWV1,  s_v1,      wave, lane); // x_v1
    proj<64, 32, 68, 68>(s_xf,       wb + OWQ1C, wlo + OWQ1C, s_cat + 32, wave, lane); // q1c
    proj<64, 32, 68, 34>(s_xf,       wb + OWK1C, wlo + OWK1C, s_k2,      wave, lane); // k1c
    __syncthreads();

    // ---- S3: pan MHA (8 heads, d=4, seq=64). wave w: heads w, w+4. ----
#pragma unroll
    for (int hh = 0; hh < 2; ++hh) {
        const int h = wave + hh * 4;
        const float* qp = s_qk + lane * 66 + 4 * h;
        float q0 = qp[0], q1 = qp[1], q2 = qp[2], q3 = qp[3];
        const float4* pp4 = (const float4*)(posi + h * 4096 + lane * 64);
        float lrow[64];
        float s = 0.f;
#pragma unroll
        for (int t4 = 0; t4 < 16; ++t4) {
            float4 pv = pp4[t4];
            float pvv[4] = {pv.x, pv.y, pv.z, pv.w};
#pragma unroll
            for (int u = 0; u < 4; ++u) {
                const int t = t4 * 4 + u;
                const float* kp = s_qk + t * 66 + 32 + 4 * h;  // pan_k, broadcast
                float d = q0 * kp[0] + q1 * kp[1] + q2 * kp[2] + q3 * kp[3];
                float e = __expf(d * scale + pvv[u]);
                lrow[t] = e; s += e;
            }
        }
        const float inv = 1.f / s;
        float o0 = 0.f, o1 = 0.f, o2 = 0.f, o3 = 0.f;
#pragma unroll
        for (int t = 0; t < 64; ++t) {
            const float* vp = s_v1 + t * 66 + 4 * h;  // v1_pan, broadcast
            float p = lrow[t];
            o0 += p * vp[0]; o1 += p * vp[1]; o2 += p * vp[2]; o3 += p * vp[3];
        }
        float* op = s_cat + lane * 68 + 4 * h;  // cat cols [0,32)
        op[0] = o0 * inv; op[1] = o1 * inv; op[2] = o2 * inv; op[3] = o3 * inv;
    }

    // ---- S5: color MHA (seq=32 channels, d=8 token-dims).
    // wave w: heads 2w (lanes 0-31), 2w+1 (lanes 32-63). Head h touches only
    // rows 8h..8h+7 == own wave's strip -> no cross-wave deps here.
    {
        const int h = wave * 2 + (lane >> 5);
        const int i = lane & 31;
        float q[8];
#pragma unroll
        for (int j = 0; j < 8; ++j) q[j] = s_cat[(8 * h + j) * 68 + 32 + i];  // q1c
        float lr[32];
#pragma unroll
        for (int j = 0; j < 8; ++j) {
            const float* kp = s_k2 + (8 * h + j) * 34;  // k1c row, broadcast
            const float qj = q[j];
#pragma unroll
            for (int t = 0; t < 32; ++t) {
                float kv = kp[t];
                if (j == 0) lr[t] = qj * kv; else lr[t] += qj * kv;
            }
        }
        const float4* pp4 = (const float4*)(posc + h * 1024 + i * 32);
        float s = 0.f;
#pragma unroll
        for (int t4 = 0; t4 < 8; ++t4) {
            float4 pv = pp4[t4];
            float pvv[4] = {pv.x, pv.y, pv.z, pv.w};
#pragma unroll
            for (int u = 0; u < 4; ++u) {
                const int t = t4 * 4 + u;
                float e = __expf(lr[t] * scale + pvv[u]);
                lr[t] = e; s += e;
            }
        }
        const float inv = 1.f / s;
#pragma unroll
        for (int j = 0; j < 8; ++j) {
            const float* vp = s_v1 + (8 * h + j) * 66 + 32;  // v1_color
            float acc = 0.f;
#pragma unroll
            for (int t = 0; t < 32; ++t) acc += lr[t] * vp[t];
            s_cat[(8 * h + j) * 68 + 32 + i] = acc * inv;  // cat cols [32,64)
        }
    }
    __syncthreads();

    // ---- Phase C: out1 = cat@Wio^T ; x_v2 = out1@Wv2^T ; x_k2 = out1@Wk2^T ----
    proj<64, 64, 68, 68>(s_cat, wb + OWIO, wlo + OWIO, s_xf, wave, lane);  // out1
    proj<64, 64, 68, 66>(s_xf,  wb + OWV2, wlo + OWV2, s_v1, wave, lane);  // x_v2
    proj<64, 32, 68, 34>(s_xf,  wb + OWK2, wlo + OWK2, s_k2, wave, lane);  // x_k2
    __syncthreads();

    // ---- S8: inter attention (cosine gate). thread -> (token t, heads wave, wave+4) ----
    {
        const int t = tid & 63;
        const int hb = tid >> 6;
#pragma unroll
        for (int r = 0; r < 2; ++r) {
            const int h = hb + r * 4;
            const float* qp = s_qk + t * 66 + 4 * h;   // pan_q
            const float* kp = s_k2 + t * 34 + 4 * h;   // x_k2
            float q0 = qp[0], q1 = qp[1], q2 = qp[2], q3 = qp[3];
            float k0 = kp[0], k1 = kp[1], k2 = kp[2], k3 = kp[3];
            float qq = q0 * q0 + q1 * q1 + q2 * q2 + q3 * q3;
            float kk = k0 * k0 + k1 * k1 + k2 * k2 + k3 * k3;
            float qk = q0 * k0 + q1 * k1 + q2 * k2 + q3 * k3;
            float cosv = qk * rsqrtf(qq * kk);
            const float* vp = s_v1 + t * 66 + 8 * h;   // x_v2
            float* op = s_cat + t * 68 + 8 * h;        // out2
#pragma unroll
            for (int j = 0; j < 8; ++j) op[j] = cosv * vp[j];
        }
    }
    __syncthreads();

    // ---- S9: final = out2 @ Wint^T -> s_v1 ----
    proj<64, 64, 68, 66>(s_cat, wb + OWINT, wlo + OWINT, s_v1, wave, lane);
    __syncthreads();

    // ---- store: LDS transpose -> coalesced fp32 float4 stores ----
    {
        const int c = tid >> 2, i = tid & 3;
        float* op = out + (size_t)b * CHW + (size_t)c * HWsz + (size_t)h0 * WWD + w0;
#pragma unroll
        for (int r = 0; r < 2; ++r) {
            const int hl = i * 2 + r;
            float v[8];
#pragma unroll
            for (int wl = 0; wl < 8; ++wl)
                v[wl] = s_v1[(hl * 8 + wl) * 66 + c];
            float4* q = (float4*)(op + hl * WWD);
            float4 q0; q0.x = v[0]; q0.y = v[1]; q0.z = v[2]; q0.w = v[3];
            float4 q1; q1.x = v[4]; q1.y = v[5]; q1.z = v[6]; q1.w = v[7];
            q[0] = q0; q[1] = q1;
        }
    }
}

extern "C" void kernel_launch(void* const* d_in, const int* in_sizes, int n_in,
                              void* d_out, int out_size, void* d_ws, size_t ws_size,
                              hipStream_t stream) {
    (void)in_sizes; (void)n_in; (void)out_size; (void)ws_size;
    const float* x    = (const float*)d_in[0];
    const float* pan  = (const float*)d_in[1];
    const float* posi = (const float*)d_in[11];
    const float* posc = (const float*)d_in[12];
    unsigned short* wb = (unsigned short*)d_ws;  // 2*WTOT*2 = 98304 B of ws

    cvt_w<<<WTOT / 256, 256, 0, stream>>>(
        (const float*)d_in[2], (const float*)d_in[3], (const float*)d_in[4],
        (const float*)d_in[5], (const float*)d_in[6], (const float*)d_in[7],
        (const float*)d_in[8], (const float*)d_in[9], (const float*)d_in[10], wb);

    in2ma_main<<<4096, 256, 0, stream>>>(x, pan, posi, posc, wb, (float*)d_out);
}